// Round 5
// baseline (508.402 us; speedup 1.0000x reference)
//
#include <hip/hip_runtime.h>
#include <math.h>

// SimpleRetention bf16 MFMA, round 5:
//  - stage3 rewritten: 256(h)x128(n) tiles, 512 thr / 8 waves, shared B-panel
//    staging (6 gloads/wave/iter vs 8), grid 512 = exactly 2 blocks/CU.
//  - epilogue transcendental factorization (stage1 xpos scale chain, stage2
//    decay split gamma^(n-m) = gamma^(n-cb) * gamma^(cb-m)).
//  - stage1 (merged QKV, BK=64, xor-swizzled LDS) unchanged: at ~959 TF plateau.

typedef __attribute__((ext_vector_type(8))) short short8;
typedef __attribute__((ext_vector_type(4))) float f32x4;
typedef __attribute__((ext_vector_type(4))) unsigned short us4;

#define BM 128
#define BN 128
#define BK 64

#define LOG2_GAMMA -0.045803598f

static __device__ __forceinline__ unsigned short f2bf(float f) {
    unsigned int u = __float_as_uint(f);
    u += 0x7FFFu + ((u >> 16) & 1u);   // RNE
    return (unsigned short)(u >> 16);
}

static __device__ __forceinline__ void gload16(const unsigned short* g, unsigned short* l) {
    __builtin_amdgcn_global_load_lds(
        (const __attribute__((address_space(1))) unsigned int*)g,
        (__attribute__((address_space(3))) unsigned int*)l, 16, 0, 0);
}

// STAGE: 1 = merged QKV projection (xpos on Q/K, V transposed store)
//        3 = att (decay+causal, bf16, zero upper blocks)
template <int STAGE>
__global__ __launch_bounds__(256)
void gemm_bt(const unsigned short* __restrict__ A,
             const unsigned short* __restrict__ Bt,
             void* __restrict__ Cv,
             unsigned short* __restrict__ Cq,
             unsigned short* __restrict__ Ck,
             unsigned short* __restrict__ Cvt,
             int lda, int ldb, int Kd,
             long long sA, long long sB, long long sC)
{
    constexpr int S = 2048, H = 2048;
    const int rowBase = blockIdx.y * BM;
    const int colBase = blockIdx.x * BN;

    if (STAGE == 3 && blockIdx.x > blockIdx.y) { // strictly-upper: zeros
        unsigned short* att = (unsigned short*)Cv + (long long)blockIdx.z * sC;
        int r = threadIdx.x >> 1, c = (threadIdx.x & 1) * 64;
        unsigned short* p = att + (size_t)(rowBase + r) * S + colBase + c;
        uint4 z = make_uint4(0, 0, 0, 0);
#pragma unroll
        for (int q = 0; q < 8; ++q) ((uint4*)p)[q] = z;
        return;
    }

    A  += (long long)blockIdx.z * sA;
    Bt += (long long)blockIdx.z * sB;

    __shared__ unsigned short As[BM * BK]; // row-major [128][64], chunks xor-swizzled
    __shared__ unsigned short Bs[BN * BK];

    const int tid  = threadIdx.x;
    const int wave = tid >> 6;
    const int lane = tid & 63;
    const int wm = (wave & 1) * 64;
    const int wn = (wave >> 1) * 64;

    f32x4 acc[4][4];
#pragma unroll
    for (int i = 0; i < 4; ++i)
#pragma unroll
        for (int j = 0; j < 4; ++j) acc[i][j] = (f32x4){0.f, 0.f, 0.f, 0.f};

    const int kmax = Kd;

    // Staging: wave w covers rows [w*32, w*32+32); src chunk xor-swizzled so
    // LDS chunk position p holds source chunk p ^ (row&7).
    const int srow = wave * 32 + (lane >> 3);
    const int schunk = ((lane & 7) ^ ((lane >> 3) & 7)) * 8;
    const unsigned short* ga = A  + (size_t)(rowBase + srow) * lda + schunk;
    const unsigned short* gb = Bt + (size_t)(colBase + srow) * ldb + schunk;
    unsigned short* lA = As + wave * 2048;
    unsigned short* lB = Bs + wave * 2048;

#pragma unroll
    for (int q = 0; q < 4; ++q) {
        gload16(ga + (size_t)q * 8 * lda, lA + q * 512);
        gload16(gb + (size_t)q * 8 * ldb, lB + q * 512);
    }

    const int fr = lane & 15;
    const int qd = lane >> 4;        // quad 0..3
    const int fsw = fr & 7;          // xor key

    for (int k0 = 0; k0 < kmax; k0 += BK) {
        __syncthreads();
        short8 af0[4], bf0[4], af1[4], bf1[4];
#pragma unroll
        for (int i = 0; i < 4; ++i) {
            int row = wm + i * 16 + fr;
            af0[i] = *(const short8*)&As[row * 64 + ((qd ^ fsw) * 8)];
            af1[i] = *(const short8*)&As[row * 64 + (((4 + qd) ^ fsw) * 8)];
        }
#pragma unroll
        for (int j = 0; j < 4; ++j) {
            int row = wn + j * 16 + fr;
            bf0[j] = *(const short8*)&Bs[row * 64 + ((qd ^ fsw) * 8)];
            bf1[j] = *(const short8*)&Bs[row * 64 + (((4 + qd) ^ fsw) * 8)];
        }
        __syncthreads();
        if (k0 + BK < kmax) {
            const unsigned short* ga2 = ga + k0 + BK;
            const unsigned short* gb2 = gb + k0 + BK;
#pragma unroll
            for (int q = 0; q < 4; ++q) {
                gload16(ga2 + (size_t)q * 8 * lda, lA + q * 512);
                gload16(gb2 + (size_t)q * 8 * ldb, lB + q * 512);
            }
        }
#pragma unroll
        for (int i = 0; i < 4; ++i)
#pragma unroll
            for (int j = 0; j < 4; ++j)
                acc[i][j] = __builtin_amdgcn_mfma_f32_16x16x32_bf16(af0[i], bf0[j], acc[i][j], 0, 0, 0);
#pragma unroll
        for (int i = 0; i < 4; ++i)
#pragma unroll
            for (int j = 0; j < 4; ++j)
                acc[i][j] = __builtin_amdgcn_mfma_f32_16x16x32_bf16(af1[i], bf1[j], acc[i][j], 0, 0, 0);
    }

    // C/D layout: col = lane&15, row = (lane>>4)*4 + reg
    if (STAGE == 1) {
        const int mode = colBase >> 11; // 0=Q, 1=K, 2=V
        if (mode < 2) {
            unsigned short* Co = (mode == 0) ? Cq : Ck;
            const float psgn = (mode == 1) ? -1.953125e-3f : 1.953125e-3f; // ±1/512
#pragma unroll
            for (int j = 0; j < 4; ++j) {
                int gc = (colBase & 2047) + wn + j * 16 + fr;
                float c0 = (float)(gc & ~1);
                float l2sv = log2f((c0 + 819.2f) * (1.0f / 2867.2f)) * psgn;
                float sstep = exp2f(l2sv);                // scale ratio per row
                float invf = exp2f(c0 * -0.0064881407f);  // 10000^(-c0/2048)
                float s1, c1;
                sincosf(invf, &s1, &c1);
#pragma unroll
                for (int i = 0; i < 4; ++i) {
                    int gr0 = rowBase + wm + i * 16 + qd * 4;
                    float fn = (float)(gr0 & (S - 1));
                    float sN, cN;
                    sincosf(fn * invf, &sN, &cN);
                    float scale = exp2f(fn * l2sv);
#pragma unroll
                    for (int r = 0; r < 4; ++r) {
                        float cs = cN * scale, ss = sN * scale;
                        float v = acc[i][j][r];
                        float o = __shfl_xor(v, 1);
                        float res = (gc & 1) ? fmaf(v, cs, o * ss) : fmaf(v, cs, -o * ss);
                        Co[(size_t)(gr0 + r) * H + gc] = f2bf(res);
                        float sn2 = sN * c1 + cN * s1; // rotate by invf
                        cN = cN * c1 - sN * s1;
                        sN = sn2;
                        scale *= sstep;
                    }
                }
            }
        } else { // V: store transposed Vt[h][8192]
#pragma unroll
            for (int j = 0; j < 4; ++j) {
                int gh = (colBase & 2047) + wn + j * 16 + fr;
#pragma unroll
                for (int i = 0; i < 4; ++i) {
                    int gm0 = rowBase + wm + i * 16 + qd * 4;
                    us4 p;
#pragma unroll
                    for (int r = 0; r < 4; ++r) p[r] = f2bf(acc[i][j][r]);
                    *(us4*)&Cvt[(size_t)gh * 8192 + gm0] = p;
                }
            }
        }
    } else { // STAGE 3: decay epilogue, factored transcendentals
        unsigned short* att = (unsigned short*)Cv + (long long)blockIdx.z * sC;
        float fj[4];
#pragma unroll
        for (int j = 0; j < 4; ++j) { // gamma^(colBase - m) in [1, 56.6]
            int m = colBase + wn + j * 16 + fr;
            fj[j] = exp2f((float)(colBase - m) * LOG2_GAMMA);
        }
#pragma unroll
        for (int i = 0; i < 4; ++i) {
            int n0 = rowBase + wm + i * 16 + qd * 4;
#pragma unroll
            for (int r = 0; r < 4; ++r) {
                float ei = exp2f((float)(n0 + r - colBase) * LOG2_GAMMA);
#pragma unroll
                for (int j = 0; j < 4; ++j) {
                    int m = colBase + wn + j * 16 + fr;
                    int d = n0 + r - m;
                    float v = (d >= 0) ? acc[i][j][r] * ei * fj[j] : 0.0f;
                    att[(size_t)(n0 + r) * S + m] = f2bf(v);
                }
            }
        }
    }
}

// stage 3: out^T tiles 256(h) x 128(n), 512 threads / 8 waves.
// A = Vt[2048][8192] (+batch col offset), B = att rows n, C = out[n][h] fp32.
__global__ __launch_bounds__(512)
void gemm_out(const unsigned short* __restrict__ Vt,
              const unsigned short* __restrict__ attB,
              float* __restrict__ Outp)
{
    constexpr int S = 2048, H = 2048;
    const int rowBase = blockIdx.y * 256;       // h
    const int colBase = blockIdx.x * 128;       // n
    const int z = blockIdx.z;

    const unsigned short* A  = Vt + (size_t)z * 2048;          // column offset (m)
    const unsigned short* Bt = attB + (size_t)z * S * S;
    float* Co = Outp + (size_t)z * S * H;

    __shared__ unsigned short As[256 * BK]; // 32 KB
    __shared__ unsigned short Bs[128 * BK]; // 16 KB

    const int tid  = threadIdx.x;
    const int wave = tid >> 6;
    const int lane = tid & 63;
    const int wm = (wave & 3) * 64;  // h within 256
    const int wn = (wave >> 2) * 64; // n within 128

    f32x4 acc[4][4];
#pragma unroll
    for (int i = 0; i < 4; ++i)
#pragma unroll
        for (int j = 0; j < 4; ++j) acc[i][j] = (f32x4){0.f, 0.f, 0.f, 0.f};

    const int kmax = colBase + 128; // causal: att[n][m]=0 for m>n

    const int subrow = lane >> 3;
    const int schunk = ((lane & 7) ^ (subrow & 7)) * 8;
    // A staging: wave stages 32 h-rows (4 gloads); B: 16 n-rows (2 gloads)
    const unsigned short* ga = A  + (size_t)(rowBase + wave * 32 + subrow) * 8192 + schunk;
    const unsigned short* gb = Bt + (size_t)(colBase + wave * 16 + subrow) * S + schunk;
    unsigned short* lA = As + wave * 2048;
    unsigned short* lB = Bs + wave * 1024;

#pragma unroll
    for (int q = 0; q < 4; ++q) gload16(ga + (size_t)q * 8 * 8192, lA + q * 512);
#pragma unroll
    for (int q = 0; q < 2; ++q) gload16(gb + (size_t)q * 8 * S, lB + q * 512);

    const int fr = lane & 15;
    const int qd = lane >> 4;
    const int fsw = fr & 7;

    for (int k0 = 0; k0 < kmax; k0 += BK) {
        __syncthreads();
        short8 af0[4], bf0[4], af1[4], bf1[4];
#pragma unroll
        for (int i = 0; i < 4; ++i) {
            int row = wm + i * 16 + fr;
            af0[i] = *(const short8*)&As[row * 64 + ((qd ^ fsw) * 8)];
            af1[i] = *(const short8*)&As[row * 64 + (((4 + qd) ^ fsw) * 8)];
        }
#pragma unroll
        for (int j = 0; j < 4; ++j) {
            int row = wn + j * 16 + fr;
            bf0[j] = *(const short8*)&Bs[row * 64 + ((qd ^ fsw) * 8)];
            bf1[j] = *(const short8*)&Bs[row * 64 + (((4 + qd) ^ fsw) * 8)];
        }
        __syncthreads();
        if (k0 + BK < kmax) {
            const unsigned short* ga2 = ga + k0 + BK;
            const unsigned short* gb2 = gb + k0 + BK;
#pragma unroll
            for (int q = 0; q < 4; ++q) gload16(ga2 + (size_t)q * 8 * 8192, lA + q * 512);
#pragma unroll
            for (int q = 0; q < 2; ++q) gload16(gb2 + (size_t)q * 8 * S, lB + q * 512);
        }
#pragma unroll
        for (int i = 0; i < 4; ++i)
#pragma unroll
            for (int j = 0; j < 4; ++j)
                acc[i][j] = __builtin_amdgcn_mfma_f32_16x16x32_bf16(af0[i], bf0[j], acc[i][j], 0, 0, 0);
#pragma unroll
        for (int i = 0; i < 4; ++i)
#pragma unroll
            for (int j = 0; j < 4; ++j)
                acc[i][j] = __builtin_amdgcn_mfma_f32_16x16x32_bf16(af1[i], bf1[j], acc[i][j], 0, 0, 0);
    }

    // C rows = h, cols = n; store out[n][h] as f32x4 (64-B segments per quad)
#pragma unroll
    for (int j = 0; j < 4; ++j) {
        int gn = colBase + wn + j * 16 + fr;
#pragma unroll
        for (int i = 0; i < 4; ++i) {
            int gh0 = rowBase + wm + i * 16 + qd * 4;
            *(f32x4*)&Co[(size_t)gn * H + gh0] = acc[i][j];
        }
    }
}

__global__ __launch_bounds__(256)
void cvt_f32_bf16(const float* __restrict__ x, unsigned short* __restrict__ y) {
    int i = blockIdx.x * 256 + threadIdx.x;
    float4 v = ((const float4*)x)[i];
    us4 o = {f2bf(v.x), f2bf(v.y), f2bf(v.z), f2bf(v.w)};
    ((us4*)y)[i] = o;
}

// three W [2048][2048] fp32 -> WtAll [6144][2048] bf16 (transposed per chunk)
__global__ __launch_bounds__(256)
void cvt_transpose3(const float* __restrict__ W0, const float* __restrict__ W1,
                    const float* __restrict__ W2, unsigned short* __restrict__ Wt) {
    __shared__ float t[64][65];
    const float* W = (blockIdx.z == 0) ? W0 : (blockIdx.z == 1) ? W1 : W2;
    unsigned short* Wo = Wt + (size_t)blockIdx.z * 4194304;
    int bx = blockIdx.x * 64, by = blockIdx.y * 64;
    int tx = threadIdx.x & 63, ty = threadIdx.x >> 6;
#pragma unroll
    for (int r = 0; r < 64; r += 4)
        t[ty + r][tx] = W[(size_t)(by + ty + r) * 2048 + bx + tx];
    __syncthreads();
#pragma unroll
    for (int r = 0; r < 64; r += 4)
        Wo[(size_t)(bx + ty + r) * 2048 + by + tx] = f2bf(t[tx][ty + r]);
}

extern "C" void kernel_launch(void* const* d_in, const int* in_sizes, int n_in,
                              void* d_out, int out_size, void* d_ws, size_t ws_size,
                              hipStream_t stream) {
    const int S = 2048, H = 2048;
    const long long MH = 16777216;         // 8192*2048 elements
    const long long HH = 4194304;          // 2048*2048
    const long long SH = (long long)S * H;
    const long long SS = (long long)S * S;

    const float* X  = (const float*)d_in[0];
    const float* WQ = (const float*)d_in[1];
    const float* WK = (const float*)d_in[2];
    const float* WV = (const float*)d_in[3];
    float* out = (float*)d_out;

    unsigned short* Xb    = (unsigned short*)d_ws;
    unsigned short* WtAll = Xb + MH;        // [6144][2048]
    unsigned short* Qb    = WtAll + 3 * HH;
    unsigned short* Kb    = Qb + MH;
    unsigned short* Vt    = Kb + MH;        // [2048][8192]
    unsigned short* att   = Vt + MH;        // [4][2048][2048]

    cvt_f32_bf16<<<16384, 256, 0, stream>>>(X, Xb);
    cvt_transpose3<<<dim3(32, 32, 3), 256, 0, stream>>>(WQ, WK, WV, WtAll);

    // stage 1: merged QKV projection, N = 6144
    gemm_bt<1><<<dim3(48, 64), 256, 0, stream>>>(Xb, WtAll, nullptr, Qb, Kb, Vt,
                                                 H, H, H, 0, 0, 0);
    // stage 2: att = (Q K^T) * decay
    gemm_bt<3><<<dim3(16, 16, 4), 256, 0, stream>>>(Qb, Kb, att, nullptr, nullptr, nullptr,
                                                    H, H, H, SH, SH, SS);
    // stage 3: out^T = Vt x att, 256x128 tiles, 512 blocks (2/CU)
    gemm_out<<<dim3(16, 8, 4), 512, 0, stream>>>(Vt, att, out);
}